// Round 3
// baseline (346.456 us; speedup 1.0000x reference)
//
#include <hip/hip_runtime.h>

typedef unsigned short u16;
typedef __attribute__((ext_vector_type(4))) float f32x4;
typedef __attribute__((ext_vector_type(8))) short short8;

#define WIN_SZ 100
#define NWIN 41
#define NBATCH 8
#define SEQ 4096
#define DM 512
#define NHEAD 8
#define KD 64
#define NWINS (NBATCH * NWIN)    // 328
#define MROWS (NWINS * WIN_SZ)   // 32800
#define MBLKS 257                // ceil(32800/128)
#define TOKPB (NWIN * WIN_SZ)    // 4100
#define NQKV 1536

__device__ __forceinline__ u16 f2bf(float f) {
  union { float f; unsigned i; } v; v.f = f;
  unsigned r = (v.i + 0x7fffu + ((v.i >> 16) & 1u)) >> 16;
  return (u16)r;
}

// async global->LDS, 16B per lane; lds base wave-uniform (HW adds lane*16)
__device__ __forceinline__ void gl2lds16(const void* g, void* lds) {
  __builtin_amdgcn_global_load_lds(
      (const __attribute__((address_space(1))) void*)g,
      (__attribute__((address_space(3))) void*)lds, 16, 0, 0);
}

// ---------------- weights fp32 -> bf16 transposed + bias concat ----------------
__global__ void prep_k(const float* __restrict__ Wq, const float* __restrict__ Wk,
                       const float* __restrict__ Wv, const float* __restrict__ Wo,
                       const float* __restrict__ bq, const float* __restrict__ bk,
                       const float* __restrict__ bv,
                       u16* __restrict__ WqkvT, u16* __restrict__ WoT,
                       float* __restrict__ biasF, u16* __restrict__ zblk) {
  int idx = blockIdx.x * 256 + threadIdx.x;
  if (idx < NQKV * DM) {
    int n = idx >> 9, k = idx & 511;
    const float* W = (n < DM) ? Wq : ((n < 2 * DM) ? Wk : Wv);
    WqkvT[idx] = f2bf(W[k * DM + (n & 511)]);
  }
  if (idx < DM * DM) WoT[idx] = f2bf(Wo[(idx & 511) * DM + (idx >> 9)]);
  if (idx < DM) biasF[idx] = bq[idx];
  else if (idx < 2 * DM) biasF[idx] = bk[idx - DM];
  else if (idx < 3 * DM) biasF[idx] = bv[idx - 2 * DM];
  if (idx < 128) zblk[idx] = 0;   // 256 B of zeros (frag source for pad rows)
}

// ---------------- GEMM: C[M,N] = A[M,512] @ Bt[N,512]^T + bias ----------------
// AFP32=1: A = fp32 x with window-padding gather + in-kernel bf16 convert.
// AFP32=0: A = bf16 rows (obuf), rows >= MROWS read zero block.
// OUTF32: fp32 vs bf16 output.
template <int AFP32, int OUTF32>
__global__ __launch_bounds__(256, 2)
void gemm_k(const void* __restrict__ Asrc, const u16* __restrict__ Bt,
            const float* __restrict__ bias, const u16* __restrict__ zsrc,
            void* __restrict__ Cout, int Ntot) {
  __shared__ u16 Alds[128 * 64];
  __shared__ u16 Blds[128 * 64];

  const int t = threadIdx.x;
  const int w = t >> 6;
  const int l = t & 63;
  const int nb = blockIdx.x, mb = blockIdx.y;
  const int m0 = mb * 128, n0 = nb * 128;
  const int lr = t >> 3;           // 0..31 (row within 32-row group)
  const int lc = (t & 7) * 8;      // element offset within 64-wide k-slab

  const float* afrow[4];
  const u16* abrow[4];
  const u16* bbase[4];
#pragma unroll
  for (int i = 0; i < 4; ++i) {
    int m = m0 + i * 32 + lr;
    if (AFP32) {
      int b = m / TOKPB, tk = m - b * TOKPB;
      afrow[i] = (m < MROWS && tk < SEQ)
                     ? ((const float*)Asrc + (size_t)(b * SEQ + tk) * DM)
                     : nullptr;
    } else {
      abrow[i] = (m < MROWS) ? ((const u16*)Asrc + (size_t)m * DM) : nullptr;
    }
    bbase[i] = Bt + (size_t)(n0 + i * 32 + lr) * DM;
  }

  f32x4 acc[4][4] = {};
  const int wm = (w & 1) * 64;
  const int wn = (w >> 1) * 64;
  const int q = l >> 4, cl = l & 15;

  for (int k0 = 0; k0 < DM; k0 += 64) {
    __syncthreads();
    // B tile: async global->LDS
#pragma unroll
    for (int i = 0; i < 4; ++i)
      gl2lds16(bbase[i] + k0 + lc, &Blds[(i * 32 + w * 8) * 64]);
    // A tile
    if (AFP32) {
#pragma unroll
      for (int i = 0; i < 4; ++i) {
        float4 v0 = make_float4(0.f, 0.f, 0.f, 0.f), v1 = v0;
        if (afrow[i]) {
          v0 = *(const float4*)(afrow[i] + k0 + lc);
          v1 = *(const float4*)(afrow[i] + k0 + lc + 4);
        }
        union { u16 s[8]; uint4 v; } o;
        o.s[0] = f2bf(v0.x); o.s[1] = f2bf(v0.y);
        o.s[2] = f2bf(v0.z); o.s[3] = f2bf(v0.w);
        o.s[4] = f2bf(v1.x); o.s[5] = f2bf(v1.y);
        o.s[6] = f2bf(v1.z); o.s[7] = f2bf(v1.w);
        *(uint4*)&Alds[(i * 32 + lr) * 64 + lc] = o.v;
      }
    } else {
#pragma unroll
      for (int i = 0; i < 4; ++i)
        gl2lds16(abrow[i] ? (abrow[i] + k0 + lc) : zsrc,
                 &Alds[(i * 32 + w * 8) * 64]);
    }
    __syncthreads();
#pragma unroll
    for (int ks = 0; ks < 2; ++ks) {
      short8 av[4], bv_[4];
      const int ko = ks * 32 + q * 8;
#pragma unroll
      for (int mi = 0; mi < 4; ++mi)
        av[mi] = *(const short8*)&Alds[(wm + mi * 16 + cl) * 64 + ko];
#pragma unroll
      for (int ni = 0; ni < 4; ++ni)
        bv_[ni] = *(const short8*)&Blds[(wn + ni * 16 + cl) * 64 + ko];
#pragma unroll
      for (int mi = 0; mi < 4; ++mi)
#pragma unroll
        for (int ni = 0; ni < 4; ++ni)
          acc[mi][ni] = __builtin_amdgcn_mfma_f32_16x16x32_bf16(
              av[mi], bv_[ni], acc[mi][ni], 0, 0, 0);
    }
  }

#pragma unroll
  for (int mi = 0; mi < 4; ++mi) {
#pragma unroll
    for (int ni = 0; ni < 4; ++ni) {
      int col = n0 + wn + ni * 16 + cl;
      float bb = bias[col];
#pragma unroll
      for (int r = 0; r < 4; ++r) {
        int row = m0 + wm + mi * 16 + q * 4 + r;
        if (row < MROWS) {
          if (OUTF32)
            ((float*)Cout)[(size_t)row * Ntot + col] = acc[mi][ni][r] + bb;
          else
            ((u16*)Cout)[(size_t)row * Ntot + col] = f2bf(acc[mi][ni][r] + bb);
        }
      }
    }
  }
}

// ---------------- per-(window, head) attention ----------------
// Q/K MFMA fragments load 16B-contiguous direct from global qkv (no LDS).
// LDS only for V^T (transpose) and P (C-layout -> A-layout round trip).
#define PS 136   // P / Vt LDS row stride (u16)

__global__ __launch_bounds__(256, 3)
void attn_k(const u16* __restrict__ qkv, const u16* __restrict__ zblk,
            u16* __restrict__ obuf) {
  __shared__ u16 Vt[64 * PS];     // 17408 B
  __shared__ u16 P[112 * PS];     // 30464 B

  const int win = blockIdx.x, h = blockIdx.y;
  const int t = threadIdx.x, w = t >> 6, l = t & 63;
  const int q = l >> 4, cl = l & 15;
  const size_t base = (size_t)win * WIN_SZ * NQKV;
  const int qoff = h * KD, koff = DM + h * KD, voff = 2 * DM + h * KD;

  // stage V^T (scalar transpose) + zero pads
  {
    const int lr4 = t >> 3, lc8 = (t & 7) * 8;
#pragma unroll
    for (int i = 0; i < 4; ++i) {
      int r = i * 32 + lr4;
      if (r < WIN_SZ) {
        uint4 vv = *(const uint4*)(qkv + base + (size_t)r * NQKV + voff + lc8);
        const u16* pv = (const u16*)&vv;
#pragma unroll
        for (int j = 0; j < 8; ++j) Vt[(lc8 + j) * PS + r] = pv[j];
      }
    }
    for (int idx = t; idx < 64 * 36; idx += 256) {   // Vt cols 100..135 = 0
      Vt[(idx / 36) * PS + WIN_SZ + idx % 36] = 0;
    }
    for (int idx = t; idx < 112 * 24; idx += 256) {  // P cols 112..135 = 0
      P[(idx / 24) * PS + 112 + idx % 24] = 0;
    }
  }

  // wave w owns m-tiles {w, w+4} (wave 3: just {3}); 7 m-tiles cover 112 rows
  const int nmt = (w < 3) ? 2 : 1;
  const int mt0 = w, mt1 = w + 4;

  // S = Q K^T : fragments direct from global
  f32x4 accs[2][7];
#pragma unroll
  for (int im = 0; im < 2; ++im) {
    if (im < nmt) {
      const int mt = (im == 0) ? mt0 : mt1;
      const int row = mt * 16 + cl;
      const u16* qp = (row < WIN_SZ)
                          ? (qkv + base + (size_t)row * NQKV + qoff + q * 8)
                          : zblk;
      short8 a0 = *(const short8*)qp;
      short8 a1 = *(const short8*)(qp + 32);
#pragma unroll
      for (int nt = 0; nt < 7; ++nt) {
        const int col = nt * 16 + cl;
        const u16* kp = (col < WIN_SZ)
                            ? (qkv + base + (size_t)col * NQKV + koff + q * 8)
                            : zblk;
        short8 b0 = *(const short8*)kp;
        short8 b1 = *(const short8*)(kp + 32);
        f32x4 c = {};
        c = __builtin_amdgcn_mfma_f32_16x16x32_bf16(a0, b0, c, 0, 0, 0);
        c = __builtin_amdgcn_mfma_f32_16x16x32_bf16(a1, b1, c, 0, 0, 0);
        accs[im][nt] = c;
      }
    }
  }

  // softmax over cols 0..99 (100..111 masked), fully in registers.
  const float scale = 0.125f;  // 1/sqrt(64)
#pragma unroll
  for (int im = 0; im < 2; ++im) {
    if (im < nmt) {
#pragma unroll
      for (int r = 0; r < 4; ++r) {
        float mx = -1e30f;
#pragma unroll
        for (int nt = 0; nt < 7; ++nt) {
          float s = accs[im][nt][r] * scale;
          if ((nt < 6) || (cl < 4)) mx = fmaxf(mx, s);
        }
        mx = fmaxf(mx, __shfl_xor(mx, 1, 64));
        mx = fmaxf(mx, __shfl_xor(mx, 2, 64));
        mx = fmaxf(mx, __shfl_xor(mx, 4, 64));
        mx = fmaxf(mx, __shfl_xor(mx, 8, 64));
        float sum = 0.f;
#pragma unroll
        for (int nt = 0; nt < 7; ++nt) {
          float s = accs[im][nt][r] * scale;
          bool valid = (nt < 6) || (cl < 4);
          float e = valid ? __expf(s - mx) : 0.f;
          accs[im][nt][r] = e;
          sum += e;
        }
        sum += __shfl_xor(sum, 1, 64);
        sum += __shfl_xor(sum, 2, 64);
        sum += __shfl_xor(sum, 4, 64);
        sum += __shfl_xor(sum, 8, 64);
        float inv = 1.0f / sum;
#pragma unroll
        for (int nt = 0; nt < 7; ++nt) accs[im][nt][r] *= inv;
      }
    }
  }

  // P: C-layout regs -> LDS (A-layout readable)
#pragma unroll
  for (int im = 0; im < 2; ++im) {
    if (im < nmt) {
      const int mt = (im == 0) ? mt0 : mt1;
#pragma unroll
      for (int nt = 0; nt < 7; ++nt)
#pragma unroll
        for (int r = 0; r < 4; ++r)
          P[(mt * 16 + q * 4 + r) * PS + nt * 16 + cl] = f2bf(accs[im][nt][r]);
    }
  }
  __syncthreads();  // Vt + P complete (single barrier in kernel)

  // O = P @ V
  f32x4 acco[2][4] = {};
#pragma unroll
  for (int ks = 0; ks < 4; ++ks) {
    const int ko = ks * 32 + q * 8;
    short8 a0 = *(const short8*)&P[(mt0 * 16 + cl) * PS + ko];
    short8 a1 = a0;
    if (nmt == 2) a1 = *(const short8*)&P[(mt1 * 16 + cl) * PS + ko];
#pragma unroll
    for (int nt = 0; nt < 4; ++nt) {
      short8 b = *(const short8*)&Vt[(nt * 16 + cl) * PS + ko];
      acco[0][nt] = __builtin_amdgcn_mfma_f32_16x16x32_bf16(a0, b, acco[0][nt], 0, 0, 0);
      if (nmt == 2)
        acco[1][nt] = __builtin_amdgcn_mfma_f32_16x16x32_bf16(a1, b, acco[1][nt], 0, 0, 0);
    }
  }

  const size_t orow0 = (size_t)win * WIN_SZ;
#pragma unroll
  for (int im = 0; im < 2; ++im) {
    if (im < nmt) {
      const int mt = (im == 0) ? mt0 : mt1;
#pragma unroll
      for (int nt = 0; nt < 4; ++nt)
#pragma unroll
        for (int r = 0; r < 4; ++r) {
          int row = mt * 16 + q * 4 + r;
          if (row < WIN_SZ)
            obuf[(orow0 + row) * DM + h * KD + nt * 16 + cl] = f2bf(acco[im][nt][r]);
        }
    }
  }
}

extern "C" void kernel_launch(void* const* d_in, const int* in_sizes, int n_in,
                              void* d_out, int out_size, void* d_ws, size_t ws_size,
                              hipStream_t stream) {
  const float* x  = (const float*)d_in[0];
  const float* Wq = (const float*)d_in[1];
  const float* bq = (const float*)d_in[2];
  const float* Wk = (const float*)d_in[3];
  const float* bk = (const float*)d_in[4];
  const float* Wv = (const float*)d_in[5];
  const float* bv = (const float*)d_in[6];
  const float* Wo = (const float*)d_in[7];
  const float* bo = (const float*)d_in[8];

  u16* ws    = (u16*)d_ws;
  u16* qkv   = ws;                            // [32800][1536] bf16 100.8 MB
  u16* obuf  = qkv + (size_t)MROWS * NQKV;    // [32800][512]  bf16  33.6 MB
  u16* WqkvT = obuf + (size_t)MROWS * DM;     // [1536][512]   bf16
  u16* WoT   = WqkvT + (size_t)NQKV * DM;     // [512][512]    bf16
  u16* zblk  = WoT + (size_t)DM * DM;         // 256 B zeros
  float* biasF = (float*)(zblk + 128);        // [1536] fp32

  prep_k<<<dim3((NQKV * DM + 255) / 256), dim3(256), 0, stream>>>(
      Wq, Wk, Wv, Wo, bq, bk, bv, WqkvT, WoT, biasF, zblk);
  gemm_k<1, 0><<<dim3(NQKV / 128, MBLKS), dim3(256), 0, stream>>>(
      x, WqkvT, biasF, zblk, qkv, NQKV);
  attn_k<<<dim3(NWINS, NHEAD), dim3(256), 0, stream>>>(qkv, zblk, obuf);
  gemm_k<0, 1><<<dim3(DM / 128, MBLKS), dim3(256), 0, stream>>>(
      obuf, WoT, bo, zblk, d_out, DM);
}

// Round 4
// 309.180 us; speedup vs baseline: 1.1206x; 1.1206x over previous
//
#include <hip/hip_runtime.h>

typedef unsigned short u16;
typedef __attribute__((ext_vector_type(4))) float f32x4;
typedef __attribute__((ext_vector_type(8))) short short8;

#define WIN_SZ 100
#define NWIN 41
#define NBATCH 8
#define SEQ 4096
#define DM 512
#define NHEAD 8
#define KD 64
#define NWINS (NBATCH * NWIN)    // 328
#define MROWS (NWINS * WIN_SZ)   // 32800
#define MBLKS 257                // ceil(32800/128)
#define TOKPB (NWIN * WIN_SZ)    // 4100
#define NQKV 1536

// ws layout (u16 element offsets)
#define OFF_XBF   0u
#define OFF_QKV   16793600u                 // MROWS*DM
#define OFF_OBUF  67174400u                 // + MROWS*NQKV
#define OFF_WQKVT 83968000u                 // + MROWS*DM
#define OFF_WOT   84754432u                 // + NQKV*DM
#define OFF_ZBLK  85016576u                 // + DM*DM
#define OFF_BIAS  85016832u                 // + 256 (fp32 bias lives here, cast)

__device__ __forceinline__ u16 f2bf(float f) {
  union { float f; unsigned i; } v; v.f = f;
  unsigned r = (v.i + 0x7fffu + ((v.i >> 16) & 1u)) >> 16;
  return (u16)r;
}

// async global->LDS, 16B per lane; lds base wave-uniform (HW adds lane*16)
__device__ __forceinline__ void gl2lds16(const void* g, void* lds) {
  __builtin_amdgcn_global_load_lds(
      (const __attribute__((address_space(1))) void*)g,
      (__attribute__((address_space(3))) void*)lds, 16, 0, 0);
}

// ---------------- weights fp32 -> bf16 transposed + bias concat ----------------
__global__ void prep_k(const float* __restrict__ Wq, const float* __restrict__ Wk,
                       const float* __restrict__ Wv, const float* __restrict__ Wo,
                       const float* __restrict__ bq, const float* __restrict__ bk,
                       const float* __restrict__ bv, u16* __restrict__ ws) {
  u16* WqkvT = ws + OFF_WQKVT;
  u16* WoT   = ws + OFF_WOT;
  u16* zblk  = ws + OFF_ZBLK;
  float* biasF = (float*)(ws + OFF_BIAS);
  int idx = blockIdx.x * 256 + threadIdx.x;
  if (idx < NQKV * DM) {
    int n = idx >> 9, k = idx & 511;
    const float* W = (n < DM) ? Wq : ((n < 2 * DM) ? Wk : Wv);
    WqkvT[idx] = f2bf(W[k * DM + (n & 511)]);
  }
  if (idx < DM * DM) WoT[idx] = f2bf(Wo[(idx & 511) * DM + (idx >> 9)]);
  if (idx < DM) biasF[idx] = bq[idx];
  else if (idx < 2 * DM) biasF[idx] = bk[idx - DM];
  else if (idx < 3 * DM) biasF[idx] = bv[idx - 2 * DM];
  if (idx < 128) zblk[idx] = 0;
}

// ---------------- x fp32 -> bf16 with window-padding gather ----------------
__global__ void convx_k(const float* __restrict__ x, u16* __restrict__ ws) {
  u16* xbf = ws + OFF_XBF;
  int i = blockIdx.x * 256 + threadIdx.x;     // float4-group index
  if (i >= MROWS * 128) return;
  int m = i >> 7;
  int c4 = (i & 127) * 4;
  int b = m / TOKPB, tk = m - b * TOKPB;
  float4 v = make_float4(0.f, 0.f, 0.f, 0.f);
  if (tk < SEQ) v = *(const float4*)(x + (size_t)(b * SEQ + tk) * DM + c4);
  u16 o[4] = {f2bf(v.x), f2bf(v.y), f2bf(v.z), f2bf(v.w)};
  *(uint2*)(xbf + (size_t)m * DM + c4) = *(const uint2*)o;
}

// ---------------- GEMM: C[M,N] = A[M,512] @ Bt[N,512]^T + bias ----------------
// A, Bt, bias, zero block all addressed as 32-bit element offsets off ws base.
// OUTF32=1: fp32 out to Cout; OUTF32=0: bf16 out to (u16*)Cout.
template <int OUTF32>
__global__ __launch_bounds__(256, 4)
void gemm_k(const u16* __restrict__ ws, unsigned aoff0, unsigned btoff,
            void* __restrict__ Cout, int Ntot) {
  __shared__ u16 Alds[128 * 64];
  __shared__ u16 Blds[128 * 64];

  const int t = threadIdx.x;
  const int w = t >> 6;
  const int l = t & 63;
  const int nb = blockIdx.x, mb = blockIdx.y;
  const int m0 = mb * 128, n0 = nb * 128;
  const int lr = t >> 3;           // 0..31
  const int lc = (t & 7) * 8;      // element offset in 64-wide k-slab

  unsigned aoff[4], boff[4];
#pragma unroll
  for (int i = 0; i < 4; ++i) {
    int m = m0 + i * 32 + lr;
    aoff[i] = (m < MROWS) ? (aoff0 + (unsigned)m * DM + lc) : (OFF_ZBLK);
    boff[i] = btoff + (unsigned)(n0 + i * 32 + lr) * DM + lc;
  }

  f32x4 acc[4][4] = {};
  const int wm = (w & 1) * 64;
  const int wn = (w >> 1) * 64;
  const int q = l >> 4, cl = l & 15;

  for (int k0 = 0; k0 < DM; k0 += 64) {
    __syncthreads();
#pragma unroll
    for (int i = 0; i < 4; ++i) {
      gl2lds16(ws + aoff[i] + (aoff[i] == OFF_ZBLK ? 0 : k0),
               &Alds[(i * 32 + w * 8) * 64]);
      gl2lds16(ws + boff[i] + k0, &Blds[(i * 32 + w * 8) * 64]);
    }
    __syncthreads();
#pragma unroll
    for (int ks = 0; ks < 2; ++ks) {
      short8 av[4], bv_[4];
      const int ko = ks * 32 + q * 8;
#pragma unroll
      for (int mi = 0; mi < 4; ++mi)
        av[mi] = *(const short8*)&Alds[(wm + mi * 16 + cl) * 64 + ko];
#pragma unroll
      for (int ni = 0; ni < 4; ++ni)
        bv_[ni] = *(const short8*)&Blds[(wn + ni * 16 + cl) * 64 + ko];
#pragma unroll
      for (int mi = 0; mi < 4; ++mi)
#pragma unroll
        for (int ni = 0; ni < 4; ++ni)
          acc[mi][ni] = __builtin_amdgcn_mfma_f32_16x16x32_bf16(
              av[mi], bv_[ni], acc[mi][ni], 0, 0, 0);
    }
  }

  const float* biasF = (const float*)(ws + OFF_BIAS);
#pragma unroll
  for (int mi = 0; mi < 4; ++mi) {
#pragma unroll
    for (int ni = 0; ni < 4; ++ni) {
      int col = n0 + wn + ni * 16 + cl;
      float bb = biasF[col];
#pragma unroll
      for (int r = 0; r < 4; ++r) {
        int row = m0 + wm + mi * 16 + q * 4 + r;
        if (row < MROWS) {
          if (OUTF32)
            ((float*)Cout)[(size_t)row * Ntot + col] = acc[mi][ni][r] + bb;
          else
            ((u16*)Cout)[(size_t)row * Ntot + col] = f2bf(acc[mi][ni][r] + bb);
        }
      }
    }
  }
}

// ---------------- per-(window, head) attention ----------------
// Q/K MFMA fragments load 16B-contiguous direct from global qkv (no LDS).
// LDS only for V^T (transpose) and P (C-layout -> A-layout round trip).
#define PS 136   // P / Vt LDS row stride (u16)

__global__ __launch_bounds__(256, 3)
void attn_k(const u16* __restrict__ ws) {
  __shared__ u16 Vt[64 * PS];     // 17408 B
  __shared__ u16 P[112 * PS];     // 30464 B

  const u16* qkv = ws + OFF_QKV;
  const u16* zblk = ws + OFF_ZBLK;
  u16* obuf = (u16*)(ws + OFF_OBUF);

  const int win = blockIdx.x, h = blockIdx.y;
  const int t = threadIdx.x, w = t >> 6, l = t & 63;
  const int q = l >> 4, cl = l & 15;
  const size_t base = (size_t)win * WIN_SZ * NQKV;
  const int qoff = h * KD, koff = DM + h * KD, voff = 2 * DM + h * KD;

  // stage V^T (scalar transpose) + zero pads
  {
    const int lr4 = t >> 3, lc8 = (t & 7) * 8;
#pragma unroll
    for (int i = 0; i < 4; ++i) {
      int r = i * 32 + lr4;
      if (r < WIN_SZ) {
        uint4 vv = *(const uint4*)(qkv + base + (size_t)r * NQKV + voff + lc8);
        const u16* pv = (const u16*)&vv;
#pragma unroll
        for (int j = 0; j < 8; ++j) Vt[(lc8 + j) * PS + r] = pv[j];
      }
    }
    for (int idx = t; idx < 64 * 36; idx += 256)    // Vt cols 100..135 = 0
      Vt[(idx / 36) * PS + WIN_SZ + idx % 36] = 0;
    for (int idx = t; idx < 112 * 24; idx += 256)   // P cols 112..135 = 0
      P[(idx / 24) * PS + 112 + idx % 24] = 0;
  }

  // wave w owns m-tiles {w, w+4} (wave 3: just {3}); 7 m-tiles cover 112 rows
  const int nmt = (w < 3) ? 2 : 1;
  const int mt0 = w, mt1 = w + 4;

  // S = Q K^T : fragments direct from global
  f32x4 accs[2][7];
#pragma unroll
  for (int im = 0; im < 2; ++im) {
    if (im < nmt) {
      const int mt = (im == 0) ? mt0 : mt1;
      const int row = mt * 16 + cl;
      const u16* qp = (row < WIN_SZ)
                          ? (qkv + base + (size_t)row * NQKV + qoff + q * 8)
                          : zblk;
      short8 a0 = *(const short8*)qp;
      short8 a1 = *(const short8*)(qp + 32);
#pragma unroll
      for (int nt = 0; nt < 7; ++nt) {
        const int col = nt * 16 + cl;
        const u16* kp = (col < WIN_SZ)
                            ? (qkv + base + (size_t)col * NQKV + koff + q * 8)
                            : zblk;
        short8 b0 = *(const short8*)kp;
        short8 b1 = *(const short8*)(kp + 32);
        f32x4 c = {};
        c = __builtin_amdgcn_mfma_f32_16x16x32_bf16(a0, b0, c, 0, 0, 0);
        c = __builtin_amdgcn_mfma_f32_16x16x32_bf16(a1, b1, c, 0, 0, 0);
        accs[im][nt] = c;
      }
    }
  }

  // softmax over cols 0..99 (100..111 masked), fully in registers.
  const float scale = 0.125f;  // 1/sqrt(64)
#pragma unroll
  for (int im = 0; im < 2; ++im) {
    if (im < nmt) {
#pragma unroll
      for (int r = 0; r < 4; ++r) {
        float mx = -1e30f;
#pragma unroll
        for (int nt = 0; nt < 7; ++nt) {
          float s = accs[im][nt][r] * scale;
          if ((nt < 6) || (cl < 4)) mx = fmaxf(mx, s);
        }
        mx = fmaxf(mx, __shfl_xor(mx, 1, 64));
        mx = fmaxf(mx, __shfl_xor(mx, 2, 64));
        mx = fmaxf(mx, __shfl_xor(mx, 4, 64));
        mx = fmaxf(mx, __shfl_xor(mx, 8, 64));
        float sum = 0.f;
#pragma unroll
        for (int nt = 0; nt < 7; ++nt) {
          float s = accs[im][nt][r] * scale;
          bool valid = (nt < 6) || (cl < 4);
          float e = valid ? __expf(s - mx) : 0.f;
          accs[im][nt][r] = e;
          sum += e;
        }
        sum += __shfl_xor(sum, 1, 64);
        sum += __shfl_xor(sum, 2, 64);
        sum += __shfl_xor(sum, 4, 64);
        sum += __shfl_xor(sum, 8, 64);
        float inv = 1.0f / sum;
#pragma unroll
        for (int nt = 0; nt < 7; ++nt) accs[im][nt][r] *= inv;
      }
    }
  }

  // P: C-layout regs -> LDS (A-layout readable)
#pragma unroll
  for (int im = 0; im < 2; ++im) {
    if (im < nmt) {
      const int mt = (im == 0) ? mt0 : mt1;
#pragma unroll
      for (int nt = 0; nt < 7; ++nt)
#pragma unroll
        for (int r = 0; r < 4; ++r)
          P[(mt * 16 + q * 4 + r) * PS + nt * 16 + cl] = f2bf(accs[im][nt][r]);
    }
  }
  __syncthreads();  // Vt + P complete (single barrier in kernel)

  // O = P @ V
  f32x4 acco[2][4] = {};
#pragma unroll
  for (int ks = 0; ks < 4; ++ks) {
    const int ko = ks * 32 + q * 8;
    short8 a0 = *(const short8*)&P[(mt0 * 16 + cl) * PS + ko];
    short8 a1 = a0;
    if (nmt == 2) a1 = *(const short8*)&P[(mt1 * 16 + cl) * PS + ko];
#pragma unroll
    for (int nt = 0; nt < 4; ++nt) {
      short8 b = *(const short8*)&Vt[(nt * 16 + cl) * PS + ko];
      acco[0][nt] = __builtin_amdgcn_mfma_f32_16x16x32_bf16(a0, b, acco[0][nt], 0, 0, 0);
      if (nmt == 2)
        acco[1][nt] = __builtin_amdgcn_mfma_f32_16x16x32_bf16(a1, b, acco[1][nt], 0, 0, 0);
    }
  }

  const size_t orow0 = (size_t)win * WIN_SZ;
#pragma unroll
  for (int im = 0; im < 2; ++im) {
    if (im < nmt) {
      const int mt = (im == 0) ? mt0 : mt1;
#pragma unroll
      for (int nt = 0; nt < 4; ++nt)
#pragma unroll
        for (int r = 0; r < 4; ++r) {
          int row = mt * 16 + q * 4 + r;
          if (row < WIN_SZ)
            obuf[(orow0 + row) * DM + h * KD + nt * 16 + cl] = f2bf(acco[im][nt][r]);
        }
    }
  }
}

extern "C" void kernel_launch(void* const* d_in, const int* in_sizes, int n_in,
                              void* d_out, int out_size, void* d_ws, size_t ws_size,
                              hipStream_t stream) {
  const float* x  = (const float*)d_in[0];
  const float* Wq = (const float*)d_in[1];
  const float* Wk = (const float*)d_in[3];
  const float* Wv = (const float*)d_in[5];
  const float* Wo = (const float*)d_in[7];
  const float* bq = (const float*)d_in[2];
  const float* bk = (const float*)d_in[4];
  const float* bv = (const float*)d_in[6];
  const float* bo = (const float*)d_in[8];

  u16* ws = (u16*)d_ws;

  prep_k<<<dim3((NQKV * DM + 255) / 256), dim3(256), 0, stream>>>(
      Wq, Wk, Wv, Wo, bq, bk, bv, ws);
  convx_k<<<dim3((MROWS * 128 + 255) / 256), dim3(256), 0, stream>>>(x, ws);
  gemm_k<0><<<dim3(NQKV / 128, MBLKS), dim3(256), 0, stream>>>(
      ws, OFF_XBF, OFF_WQKVT, ws + OFF_QKV, NQKV);
  attn_k<<<dim3(NWINS, NHEAD), dim3(256), 0, stream>>>(ws);

  // gemm<1> bias = bo (fp32, direct input): stage it into the ws bias slot first?
  // No — reuse template by copying bo into OFF_BIAS region via a tiny kernel is
  // extra dispatch; instead pass bias through the same ws slot: prep wrote qkv
  // biases there. For the output projection we need bo, so overwrite after attn
  // would race with nothing (gemm<0>/attn already consumed biasF). Use a 1-block
  // copy kernel fused into attn? Simplest: small kernel below.
  hipMemcpyAsync(ws + OFF_BIAS, bo, DM * sizeof(float),
                 hipMemcpyDeviceToDevice, stream);
  gemm_k<1><<<dim3(DM / 128, MBLKS), dim3(256), 0, stream>>>(
      ws, OFF_OBUF, OFF_WOT, d_out, DM);
}